// Round 2
// baseline (195.809 us; speedup 1.0000x reference)
//
#include <hip/hip_runtime.h>
#include <hip/hip_bf16.h>

// Sentence rep: out[b][d] = mean over s of in[b][s][d]
// in:  [4096, 128, 512] fp32  (1.074 GB), out: [4096, 512] fp32 (8.4 MB)
//
// 2 float4 per thread: lane L of a wave handles columns L and L+64 of one
// batch row -> each wave reads a FULL contiguous 2 KiB row per seq step.
// 4096 batches x 64 threads = 262144 threads = 1024 blocks x 256.
// unroll 16 -> up to 32 outstanding float4 loads per thread for latency hiding.

__global__ __launch_bounds__(256) void sentence_rep_mean_kernel(
    const float4* __restrict__ in, float4* __restrict__ out) {
    const int t  = blockIdx.x * blockDim.x + threadIdx.x;  // 0..262143
    const int c  = t & 63;                                 // float4 col 0..63
    const int b  = t >> 6;                                 // batch 0..4095

    // per-batch stride: 128*512/4 = 16384 float4; per-seq stride: 128 float4
    const float4* row = in + (size_t)b * 16384 + c;

    float ax0 = 0.f, ay0 = 0.f, az0 = 0.f, aw0 = 0.f;
    float ax1 = 0.f, ay1 = 0.f, az1 = 0.f, aw1 = 0.f;
    #pragma unroll 16
    for (int s = 0; s < 128; ++s) {
        float4 v0 = row[(size_t)s * 128];
        float4 v1 = row[(size_t)s * 128 + 64];
        ax0 += v0.x; ay0 += v0.y; az0 += v0.z; aw0 += v0.w;
        ax1 += v1.x; ay1 += v1.y; az1 += v1.z; aw1 += v1.w;
    }

    const float scale = 1.0f / 128.0f;
    float4 r0, r1;
    r0.x = ax0 * scale; r0.y = ay0 * scale; r0.z = az0 * scale; r0.w = aw0 * scale;
    r1.x = ax1 * scale; r1.y = ay1 * scale; r1.z = az1 * scale; r1.w = aw1 * scale;
    float4* orow = out + (size_t)b * 128 + c;
    orow[0]  = r0;
    orow[64] = r1;
}

extern "C" void kernel_launch(void* const* d_in, const int* in_sizes, int n_in,
                              void* d_out, int out_size, void* d_ws, size_t ws_size,
                              hipStream_t stream) {
    const float4* in = (const float4*)d_in[0];
    float4* out = (float4*)d_out;
    // total threads = out_size/4/2 = 262144
    const int total_threads = out_size / 8;
    const int block = 256;
    const int grid = (total_threads + block - 1) / block;  // 1024
    sentence_rep_mean_kernel<<<grid, block, 0, stream>>>(in, out);
}

// Round 4
// 168.438 us; speedup vs baseline: 1.1625x; 1.1625x over previous
//
#include <hip/hip_runtime.h>
#include <hip/hip_bf16.h>

// Sentence rep: out[b][d] = mean over s of in[b][s][d]
// in:  [4096, 128, 512] fp32  (1.074 GB), out: [4096, 512] fp32 (8.4 MB)
//
// Round-1 structure (1 float4/thread, 2048 blocks x 256) + NONTEMPORAL
// loads/stores: input read exactly once -> skip cache allocation.
// NOTE: __builtin_nontemporal_* needs clang native vectors, not HIP float4.

typedef float f32x4 __attribute__((ext_vector_type(4)));

__global__ __launch_bounds__(256) void sentence_rep_mean_kernel(
    const f32x4* __restrict__ in, f32x4* __restrict__ out) {
    const int t  = blockIdx.x * blockDim.x + threadIdx.x;  // 0..524287
    const int d4 = t & 127;                                // float4 col 0..127
    const int b  = t >> 7;                                 // batch 0..4095

    // per-batch stride: 128*512/4 = 16384 f32x4; per-seq stride: 128 f32x4
    const f32x4* row = in + (size_t)b * 16384 + d4;

    f32x4 acc = {0.f, 0.f, 0.f, 0.f};
    #pragma unroll 8
    for (int s = 0; s < 128; ++s) {
        f32x4 v = __builtin_nontemporal_load(&row[(size_t)s * 128]);
        acc += v;
    }

    acc *= (1.0f / 128.0f);
    __builtin_nontemporal_store(acc, &out[t]);
}

extern "C" void kernel_launch(void* const* d_in, const int* in_sizes, int n_in,
                              void* d_out, int out_size, void* d_ws, size_t ws_size,
                              hipStream_t stream) {
    const f32x4* in = (const f32x4*)d_in[0];
    f32x4* out = (f32x4*)d_out;
    const int total_f4 = out_size / 4;                 // 524288
    const int block = 256;
    const int grid = (total_f4 + block - 1) / block;   // 2048
    sentence_rep_mean_kernel<<<grid, block, 0, stream>>>(in, out);
}